// Round 2
// baseline (4668.012 us; speedup 1.0000x reference)
//
#include <hip/hip_runtime.h>
#include <math.h>

constexpr int Bb  = 64;
constexpr int Tt  = 2048;
constexpr int INN = 128;
constexpr int HH  = 256;
constexpr int ROWS = Bb * Tt;   // 131072

// ---------------------------------------------------------------------------
// GEMM: out[row][j] = sum_k in[row][k] * W[j][k] + bias1[j] + bias2[j]
// rows = B*T, j < 256, K in {128, 256}. Tile: 64 rows x 256 cols, Kc=16,
// 256 threads, 8x8 register tile per thread. In-place safe (WG owns all 256
// cols of its 64 rows; reads of those rows complete before epilogue writes).
// ---------------------------------------------------------------------------
template <int K>
__global__ __launch_bounds__(256) void ih_gemm(const float* in, const float* W,
                                               const float* bias1, const float* bias2,
                                               float* out)
{
    __shared__ float a_lds[16][68];    // [kk][row]   (+4 pad)
    __shared__ float b_lds[16][264];   // [kk][col]   (+8 pad)

    const int tid = threadIdx.x;
    const int tx  = tid & 31;   // col group: cols tx*8 .. +8
    const int ty  = tid >> 5;   // row group: rows ty*8 .. +8
    const int row0 = blockIdx.x * 64;

    float acc[8][8];
#pragma unroll
    for (int r = 0; r < 8; ++r)
#pragma unroll
        for (int c = 0; c < 8; ++c) acc[r][c] = 0.f;

    for (int k0 = 0; k0 < K; k0 += 16) {
#pragma unroll
        for (int i = 0; i < 4; ++i) {
            int e = i * 256 + tid;
            int r = e >> 4, kk = e & 15;
            a_lds[kk][r] = in[(row0 + r) * K + k0 + kk];
        }
#pragma unroll
        for (int i = 0; i < 16; ++i) {
            int e = i * 256 + tid;
            int j = e >> 4, kk = e & 15;
            b_lds[kk][j] = W[j * K + k0 + kk];
        }
        __syncthreads();

#pragma unroll
        for (int kk = 0; kk < 16; ++kk) {
            float4 a0 = *(const float4*)&a_lds[kk][ty * 8];
            float4 a1 = *(const float4*)&a_lds[kk][ty * 8 + 4];
            float4 b0 = *(const float4*)&b_lds[kk][tx * 8];
            float4 b1 = *(const float4*)&b_lds[kk][tx * 8 + 4];
            float av[8] = {a0.x, a0.y, a0.z, a0.w, a1.x, a1.y, a1.z, a1.w};
            float bv[8] = {b0.x, b0.y, b0.z, b0.w, b1.x, b1.y, b1.z, b1.w};
#pragma unroll
            for (int r = 0; r < 8; ++r)
#pragma unroll
                for (int c = 0; c < 8; ++c)
                    acc[r][c] += av[r] * bv[c];
        }
        __syncthreads();
    }

    float bsum[8];
#pragma unroll
    for (int c = 0; c < 8; ++c) {
        int j = tx * 8 + c;
        bsum[c] = bias1[j] + bias2[j];
    }
#pragma unroll
    for (int r = 0; r < 8; ++r) {
        int row = row0 + ty * 8 + r;
        float4 o0 = make_float4(acc[r][0] + bsum[0], acc[r][1] + bsum[1],
                                acc[r][2] + bsum[2], acc[r][3] + bsum[3]);
        float4 o1 = make_float4(acc[r][4] + bsum[4], acc[r][5] + bsum[5],
                                acc[r][6] + bsum[6], acc[r][7] + bsum[7]);
        *(float4*)&out[row * HH + tx * 8]     = o0;
        *(float4*)&out[row * HH + tx * 8 + 4] = o1;
    }
}

// ---------------------------------------------------------------------------
// Recurrence, single-barrier design. In-place over xp: h_t = tanh(xp[t] + W@h).
// One WG/batch, 1024 thr = 16 waves. Wave w owns k-chunk [16w,16w+16) for the
// matvec AND the reduction of outputs j in [16w,16w+16):
//   - lane l computes partials for outputs 4l..4l+3 over its wave's k-chunk,
//     writes float4 to pbuf[t&1]  (double-buffered -> no WAR barrier needed)
//   - ONE __syncthreads
//   - lane l reduces output jr = 16w+(l&15): reads partial chunks
//     wq..wq+3 (wq = (l>>4)*4), folds replicas with shfl_xor(16),shfl_xor(32)
//   - fast tanh: 1 - 2*rcp(exp(2s)+1)  (branch-free, saturates correctly)
//   - h for next step broadcast in-wave via 16 shfl (no LDS, no 2nd barrier)
// xp[t+1] prefetched one step ahead; h_t stored to global off the critical path.
// ---------------------------------------------------------------------------
__global__ __launch_bounds__(1024) void rnn_recur(float* xp, const float* Whh)
{
    constexpr int PS = HH + 4;             // 260 floats; 260%4==0 keeps b128 align
    __shared__ float pbuf[2][16 * PS];

    const int tid = threadIdx.x;
    const int w   = tid >> 6;              // wave index = k-chunk = output-chunk
    const int l   = tid & 63;
    const int jr  = 16 * w + (l & 15);     // output this lane reduces
    const int wq  = (l >> 4) * 4;          // first partial-chunk this lane reads
    float* xpb = xp + (size_t)blockIdx.x * Tt * HH;

    // wreg[r][c] = Whh[(4l+r)*H + 16w + c]   (64 VGPRs, loaded once)
    float wreg[4][16];
#pragma unroll
    for (int r = 0; r < 4; ++r) {
        const float4* wp = (const float4*)&Whh[(4 * l + r) * HH + 16 * w];
#pragma unroll
        for (int q = 0; q < 4; ++q) {
            float4 v = wp[q];
            wreg[r][4 * q + 0] = v.x;
            wreg[r][4 * q + 1] = v.y;
            wreg[r][4 * q + 2] = v.z;
            wreg[r][4 * q + 3] = v.w;
        }
    }

    float hc[16];
#pragma unroll
    for (int c = 0; c < 16; ++c) hc[c] = 0.f;
    float xv = xpb[jr];                    // xp[t=0][jr]

#pragma unroll 1
    for (int t = 0; t < Tt; ++t) {
        // prefetch next step's xp (one full step of latency hiding)
        int tn = (t + 1 < Tt) ? (t + 1) : t;
        float xnext = xpb[tn * HH + jr];

        // matvec partials over this wave's k-chunk
        float p0 = 0.f, p1 = 0.f, p2 = 0.f, p3 = 0.f;
#pragma unroll
        for (int c = 0; c < 16; ++c) {
            p0 += wreg[0][c] * hc[c];
            p1 += wreg[1][c] * hc[c];
            p2 += wreg[2][c] * hc[c];
            p3 += wreg[3][c] * hc[c];
        }
        float* pw = &pbuf[t & 1][0];
        *(float4*)&pw[w * PS + 4 * l] = make_float4(p0, p1, p2, p3);
        __syncthreads();                   // the ONLY barrier per step

        // owner-wave reduction: 4 LDS reads (2-way bank alias = free)
        float a0 = pw[(wq + 0) * PS + jr];
        float a1 = pw[(wq + 1) * PS + jr];
        float a2 = pw[(wq + 2) * PS + jr];
        float a3 = pw[(wq + 3) * PS + jr];
        float acc = (a0 + a1) + (a2 + a3);
        acc += __shfl_xor(acc, 16, 64);    // fold 4 replica groups
        acc += __shfl_xor(acc, 32, 64);
        float s = acc + xv;

        // fast tanh: 1 - 2/(exp(2s)+1); exp->inf / ->0 saturate to +/-1
        float e  = __expf(2.f * s);
        float hn = 1.f - 2.f * __builtin_amdgcn_rcpf(e + 1.f);

        // commit h_t to global (layer output), off critical path
        if (l < 16) xpb[t * HH + jr] = hn;

        // in-wave broadcast: hc[c] = h[16w + c] for next step's matvec
#pragma unroll
        for (int c = 0; c < 16; ++c) hc[c] = __shfl(hn, c, 16);

        xv = xnext;
    }
}

// ---------------------------------------------------------------------------
// FC: out[b] = dot(h2[b][T-1][:], W_fc) + b_fc.  One wave per batch.
// ---------------------------------------------------------------------------
__global__ __launch_bounds__(64) void fc_kernel(const float* h2, const float* Wfc,
                                                const float* bfc, float* out)
{
    const int b = blockIdx.x;
    const int l = threadIdx.x;
    const float* hrow = h2 + ((size_t)b * Tt + (Tt - 1)) * HH;
    float4 hv = *(const float4*)&hrow[4 * l];
    float4 wv = *(const float4*)&Wfc[4 * l];
    float p = hv.x * wv.x + hv.y * wv.y + hv.z * wv.z + hv.w * wv.w;
#pragma unroll
    for (int off = 32; off > 0; off >>= 1) p += __shfl_down(p, off, 64);
    if (l == 0) out[b] = p + bfc[0];
}

// ---------------------------------------------------------------------------
extern "C" void kernel_launch(void* const* d_in, const int* in_sizes, int n_in,
                              void* d_out, int out_size, void* d_ws, size_t ws_size,
                              hipStream_t stream)
{
    const float* x     = (const float*)d_in[0];
    const float* W_ih0 = (const float*)d_in[1];
    const float* W_hh0 = (const float*)d_in[2];
    const float* b_ih0 = (const float*)d_in[3];
    const float* b_hh0 = (const float*)d_in[4];
    const float* W_ih1 = (const float*)d_in[5];
    const float* W_hh1 = (const float*)d_in[6];
    const float* b_ih1 = (const float*)d_in[7];
    const float* b_hh1 = (const float*)d_in[8];
    const float* W_fc  = (const float*)d_in[9];
    const float* b_fc  = (const float*)d_in[10];
    float* ws  = (float*)d_ws;                 // B*T*H floats (128 MiB)
    float* out = (float*)d_out;

    ih_gemm<INN><<<ROWS / 64, 256, 0, stream>>>(x, W_ih0, b_ih0, b_hh0, ws);
    rnn_recur<<<Bb, 1024, 0, stream>>>(ws, W_hh0);
    ih_gemm<HH><<<ROWS / 64, 256, 0, stream>>>(ws, W_ih1, b_ih1, b_hh1, ws);
    rnn_recur<<<Bb, 1024, 0, stream>>>(ws, W_hh1);
    fc_kernel<<<Bb, 64, 0, stream>>>(ws, W_fc, b_fc, out);
}